// Round 1
// baseline (314.387 us; speedup 1.0000x reference)
//
#include <hip/hip_runtime.h>

typedef __bf16 bf16;
typedef __bf16 bf16x8 __attribute__((ext_vector_type(8)));
typedef __bf16 bf16x4 __attribute__((ext_vector_type(4)));
typedef float  f32x4  __attribute__((ext_vector_type(4)));
typedef unsigned long long uptr;

#define MFMA16(a, b, c) __builtin_amdgcn_mfma_f32_16x16x32_bf16((a), (b), (c), 0, 0, 0)

// async global->LDS, 16B per lane. LDS dest is wave-uniform base + lane*16 (HW).
__device__ __forceinline__ void gl_lds16(const void* g, void* l) {
  __builtin_amdgcn_global_load_lds(
      (__attribute__((address_space(1))) void*)(uptr)(g),
      (__attribute__((address_space(3))) void*)(uptr)(l),
      16, 0, 0);
}

// ---------------------------------------------------------------------------
// fp32 -> bf16 elementwise convert (n must be a multiple of 1024)
__global__ __launch_bounds__(256) void f32_to_bf16(const float* __restrict__ in,
                                                   bf16* __restrict__ out) {
  const long i = ((long)blockIdx.x * 256 + threadIdx.x) * 4;
  const float4 v = *(const float4*)(in + i);
  bf16x4 o = {(bf16)v.x, (bf16)v.y, (bf16)v.z, (bf16)v.w};
  *(bf16x4*)(out + i) = o;
}

// memory_values [256][512] fp32 -> mvT [512][256] bf16
__global__ __launch_bounds__(256) void mv_transpose(const float* __restrict__ mv,
                                                    bf16* __restrict__ mvT) {
  const int d = blockIdx.x;   // 0..511
  const int m = threadIdx.x;  // 0..255
  mvT[(long)d * 256 + m] = (bf16)mv[(long)m * 512 + d];
}

// row softmax over 256 cols, fp32 in, bf16 out. one wave per row.
__global__ __launch_bounds__(256) void softmax_rows256(const float* __restrict__ in,
                                                       bf16* __restrict__ out) {
  const int w = threadIdx.x >> 6, l = threadIdx.x & 63;
  const long row = (long)blockIdx.x * 4 + w;
  const float4 v = *(const float4*)(in + row * 256 + l * 4);
  float mx = fmaxf(fmaxf(v.x, v.y), fmaxf(v.z, v.w));
  mx = fmaxf(mx, __shfl_xor(mx, 1, 64));
  mx = fmaxf(mx, __shfl_xor(mx, 2, 64));
  mx = fmaxf(mx, __shfl_xor(mx, 4, 64));
  mx = fmaxf(mx, __shfl_xor(mx, 8, 64));
  mx = fmaxf(mx, __shfl_xor(mx, 16, 64));
  mx = fmaxf(mx, __shfl_xor(mx, 32, 64));
  const float e0 = __expf(v.x - mx), e1 = __expf(v.y - mx);
  const float e2 = __expf(v.z - mx), e3 = __expf(v.w - mx);
  float sm = e0 + e1 + e2 + e3;
  sm += __shfl_xor(sm, 1, 64);
  sm += __shfl_xor(sm, 2, 64);
  sm += __shfl_xor(sm, 4, 64);
  sm += __shfl_xor(sm, 8, 64);
  sm += __shfl_xor(sm, 16, 64);
  sm += __shfl_xor(sm, 32, 64);
  const float inv = 1.0f / sm;
  bf16x4 o = {(bf16)(e0 * inv), (bf16)(e1 * inv), (bf16)(e2 * inv), (bf16)(e3 * inv)};
  *(bf16x4*)(out + row * 256 + l * 4) = o;
}

// ---------------------------------------------------------------------------
// C[M][N] = (A[M][K] @ B[N][K]^T + bias)*alpha (+ add)   -- m97 structure
// 128x128 tile, BK=64, 4 waves, 64x64 per wave, 16x16x32 bf16 MFMA.
// TRANS_OUT: write C transposed per batch: C[(m/2048)*N + n][*2048 + m%2048]
template <typename OutT, bool HAS_ADD, bool TRANS_OUT>
__global__ __launch_bounds__(256, 3) void gemm_bt(
    const bf16* __restrict__ A, const bf16* __restrict__ B,
    const float* __restrict__ bias, const bf16* __restrict__ addsrc,
    OutT* __restrict__ C, int M, int N, int K, float alpha) {
  __shared__ bf16 lA[128 * 64];
  __shared__ bf16 lB[128 * 64];
  const int tid = threadIdx.x;
  const int w = tid >> 6, l = tid & 63;
  const int hi = l >> 4, lo = l & 15;
  const int m0 = blockIdx.y * 128, n0 = blockIdx.x * 128;
  const int wm = (w >> 1) * 64, wn = (w & 1) * 64;

  // staging: wave w fills LDS rows [w*32, w*32+32), 4 insts of 8 rows each.
  const int sr = w * 32 + (l >> 3);   // lds/global tile row for this lane
  const int sc = (l & 7) * 8;         // element offset (16B chunk) within row
  const long aBase = (long)(m0 + sr) * K + sc;
  const long bBase = (long)(n0 + sr) * K + sc;

  f32x4 acc[4][4] = {};

  for (int k0 = 0; k0 < K; k0 += 64) {
#pragma unroll
    for (int j = 0; j < 4; ++j) {
      gl_lds16(A + aBase + (long)8 * j * K + k0, (char*)lA + (w * 32 + 8 * j) * 128);
      gl_lds16(B + bBase + (long)8 * j * K + k0, (char*)lB + (w * 32 + 8 * j) * 128);
    }
    __syncthreads();
#pragma unroll
    for (int kk = 0; kk < 2; ++kk) {
      bf16x8 af[4], bfr[4];
#pragma unroll
      for (int i = 0; i < 4; ++i) {
        af[i]  = *(const bf16x8*)((const char*)lA + (wm + i * 16 + lo) * 128 + kk * 64 + hi * 16);
        bfr[i] = *(const bf16x8*)((const char*)lB + (wn + i * 16 + lo) * 128 + kk * 64 + hi * 16);
      }
#pragma unroll
      for (int mi = 0; mi < 4; ++mi)
#pragma unroll
        for (int ni = 0; ni < 4; ++ni)
          acc[mi][ni] = MFMA16(af[mi], bfr[ni], acc[mi][ni]);
    }
    __syncthreads();
  }

#pragma unroll
  for (int ni = 0; ni < 4; ++ni) {
    const int col = n0 + wn + ni * 16 + lo;
    const float bv = bias ? bias[col] : 0.0f;
#pragma unroll
    for (int mi = 0; mi < 4; ++mi) {
      const int mrow = m0 + wm + mi * 16 + hi * 4;
#pragma unroll
      for (int r = 0; r < 4; ++r) {
        const long row = mrow + r;
        float v = (acc[mi][ni][r] + bv) * alpha;
        if (HAS_ADD) v += (float)addsrc[row * N + col];
        if (TRANS_OUT) {
          const long bb = row >> 11, ss = row & 2047;
          C[(bb * N + col) * 2048 + ss] = (OutT)v;
        } else {
          C[row * (long)N + col] = (OutT)v;
        }
      }
    }
  }
}

// ---------------------------------------------------------------------------
// Flash attention. Q,K: [B*S][H] bf16 (head h at cols h*64..). Vt: [B][H][S] bf16.
// Block: 256 thr / 4 waves; 128 Q rows per block (32 per wave); 64-key tiles.
// K/Vt tiles staged via global_load_lds with XOR-swizzled source (chunk ^= row&7),
// frags read with the same XOR -> bank-conflict-free ds_read_b128.
__global__ __launch_bounds__(256, 2) void attn_fwd(
    const bf16* __restrict__ Q, const bf16* __restrict__ Km,
    const bf16* __restrict__ Vt, const float* __restrict__ mask,
    bf16* __restrict__ AO) {
  __shared__ bf16 lK[64 * 64];      // [key][d]
  __shared__ bf16 lV[64 * 64];      // [d][key]  (from Vt)
  __shared__ bf16 lP[4][32 * 64];   // per-wave P [q][k]
  const int tid = threadIdx.x, w = tid >> 6, l = tid & 63;
  const int hi = l >> 4, lo = l & 15;
  const int b = blockIdx.z, h = blockIdx.y, q0 = blockIdx.x * 128;
  const long S = 2048, Hh = 1024;

  // Q fragments (A-frag: row=l%16, k=(l/16)*8+j), held in registers
  bf16x8 qf[2][2];
#pragma unroll
  for (int mf = 0; mf < 2; ++mf)
#pragma unroll
    for (int ds = 0; ds < 2; ++ds) {
      const long row = (long)b * S + q0 + w * 32 + mf * 16 + lo;
      qf[mf][ds] = *(const bf16x8*)(Q + row * Hh + h * 64 + ds * 32 + hi * 8);
    }

  f32x4 o[2][4] = {};
  float mrun[2][4], lrun[2][4];
#pragma unroll
  for (int mf = 0; mf < 2; ++mf)
#pragma unroll
    for (int r = 0; r < 4; ++r) { mrun[mf][r] = -1e30f; lrun[mf][r] = 0.0f; }

  // staging: wave w covers tile rows [w*16, w*16+16), 2 insts of 8 rows each.
  // swizzled source chunk: (l&7) ^ (l>>3)  (row&7 == l>>3 since bases are 8-aligned)
  const int swr = w * 16 + (l >> 3);
  const int swc = ((l & 7) ^ (l >> 3)) * 8;

  for (int k0 = 0; k0 < 2048; k0 += 64) {
#pragma unroll
    for (int j = 0; j < 2; ++j) {
      gl_lds16(Km + ((long)b * S + k0 + swr + 8 * j) * Hh + h * 64 + swc,
               (char*)lK + (w * 16 + 8 * j) * 128);
      gl_lds16(Vt + ((long)b * Hh + h * 64 + swr + 8 * j) * S + k0 + swc,
               (char*)lV + (w * 16 + 8 * j) * 128);
    }
    __syncthreads();

    float madd[4];
#pragma unroll
    for (int kf = 0; kf < 4; ++kf)
      madd[kf] = mask[(long)b * S + k0 + kf * 16 + lo] * (-1e9f);

    // S = Q K^T
    f32x4 s[2][4] = {};
#pragma unroll
    for (int kf = 0; kf < 4; ++kf) {
      const int krow = kf * 16 + lo;
#pragma unroll
      for (int ds = 0; ds < 2; ++ds) {
        const int cb = ((ds * 4 + hi) ^ (krow & 7)) * 16;
        const bf16x8 kb = *(const bf16x8*)((const char*)lK + krow * 128 + cb);
        s[0][kf] = MFMA16(qf[0][ds], kb, s[0][kf]);
        s[1][kf] = MFMA16(qf[1][ds], kb, s[1][kf]);
      }
    }
#pragma unroll
    for (int mf = 0; mf < 2; ++mf)
#pragma unroll
      for (int kf = 0; kf < 4; ++kf)
        s[mf][kf] = s[mf][kf] * 0.125f + madd[kf];

    // online softmax (row r of D-frag lives in the 16 lanes sharing l>>4)
#pragma unroll
    for (int mf = 0; mf < 2; ++mf) {
      float mx[4], f[4], rs[4];
#pragma unroll
      for (int r = 0; r < 4; ++r)
        mx[r] = fmaxf(fmaxf(s[mf][0][r], s[mf][1][r]), fmaxf(s[mf][2][r], s[mf][3][r]));
#pragma unroll
      for (int r = 0; r < 4; ++r) {
        mx[r] = fmaxf(mx[r], __shfl_xor(mx[r], 1, 64));
        mx[r] = fmaxf(mx[r], __shfl_xor(mx[r], 2, 64));
        mx[r] = fmaxf(mx[r], __shfl_xor(mx[r], 4, 64));
        mx[r] = fmaxf(mx[r], __shfl_xor(mx[r], 8, 64));
        const float mn = fmaxf(mrun[mf][r], mx[r]);
        f[r] = __expf(mrun[mf][r] - mn);
        mrun[mf][r] = mn;
      }
#pragma unroll
      for (int kf = 0; kf < 4; ++kf)
#pragma unroll
        for (int r = 0; r < 4; ++r)
          s[mf][kf][r] = __expf(s[mf][kf][r] - mrun[mf][r]);
#pragma unroll
      for (int r = 0; r < 4; ++r) {
        rs[r] = s[mf][0][r] + s[mf][1][r] + s[mf][2][r] + s[mf][3][r];
        rs[r] += __shfl_xor(rs[r], 1, 64);
        rs[r] += __shfl_xor(rs[r], 2, 64);
        rs[r] += __shfl_xor(rs[r], 4, 64);
        rs[r] += __shfl_xor(rs[r], 8, 64);
        lrun[mf][r] = lrun[mf][r] * f[r] + rs[r];
      }
#pragma unroll
      for (int df = 0; df < 4; ++df)
#pragma unroll
        for (int r = 0; r < 4; ++r) o[mf][df][r] *= f[r];
      // P (bf16) -> wave-private LDS, XOR-swizzled rows
#pragma unroll
      for (int kf = 0; kf < 4; ++kf)
#pragma unroll
        for (int r = 0; r < 4; ++r) {
          const int qrow = mf * 16 + hi * 4 + r;
          const int byt = qrow * 128 + (((kf * 16 + lo) * 2) ^ ((qrow & 7) << 4));
          *(bf16*)((char*)lP[w] + byt) = (bf16)s[mf][kf][r];
        }
    }

    // O += P V
#pragma unroll
    for (int kk = 0; kk < 2; ++kk) {
      bf16x8 pa[2];
#pragma unroll
      for (int mf = 0; mf < 2; ++mf) {
        const int qrow = mf * 16 + lo;
        const int cb = ((kk * 4 + hi) ^ (qrow & 7)) * 16;
        pa[mf] = *(const bf16x8*)((const char*)lP[w] + qrow * 128 + cb);
      }
#pragma unroll
      for (int df = 0; df < 4; ++df) {
        const int vrow = df * 16 + lo;
        const int cb = ((kk * 4 + hi) ^ (vrow & 7)) * 16;
        const bf16x8 vb = *(const bf16x8*)((const char*)lV + vrow * 128 + cb);
        o[0][df] = MFMA16(pa[0], vb, o[0][df]);
        o[1][df] = MFMA16(pa[1], vb, o[1][df]);
      }
    }
    __syncthreads();
  }

#pragma unroll
  for (int mf = 0; mf < 2; ++mf)
#pragma unroll
    for (int df = 0; df < 4; ++df)
#pragma unroll
      for (int r = 0; r < 4; ++r) {
        const long q = (long)b * S + q0 + w * 32 + mf * 16 + hi * 4 + r;
        AO[q * Hh + h * 64 + df * 16 + lo] = (bf16)(o[mf][df][r] / lrun[mf][r]);
      }
}

// ---------------------------------------------------------------------------
extern "C" void kernel_launch(void* const* d_in, const int* in_sizes, int n_in,
                              void* d_out, int out_size, void* d_ws, size_t ws_size,
                              hipStream_t stream) {
  const float* X    = (const float*)d_in[0];
  const float* mask = (const float*)d_in[1];
  const float* Wq   = (const float*)d_in[2];  const float* bq  = (const float*)d_in[3];
  const float* Wk   = (const float*)d_in[4];  const float* bk  = (const float*)d_in[5];
  const float* Wv   = (const float*)d_in[6];  const float* bv  = (const float*)d_in[7];
  const float* Wo   = (const float*)d_in[8];  const float* bo  = (const float*)d_in[9];
  const float* mv   = (const float*)d_in[10];
  const float* Wmp  = (const float*)d_in[11]; const float* bmp = (const float*)d_in[12];
  const float* Wma  = (const float*)d_in[13]; const float* bma = (const float*)d_in[14];

  char* ws = (char*)d_ws;
  size_t off = 0;
  auto alloc = [&](size_t bytes) -> void* {
    void* p = ws + off;
    off += (bytes + 255) & ~(size_t)255;
    return p;
  };
  const long MS_ = 4096;  // B*S rows
  bf16* Xb   = (bf16*)alloc(MS_ * 1024 * 2);
  bf16* Wqb  = (bf16*)alloc(1024 * 1024 * 2);
  bf16* Wkb  = (bf16*)alloc(1024 * 1024 * 2);
  bf16* Wvb  = (bf16*)alloc(1024 * 1024 * 2);
  bf16* Wob  = (bf16*)alloc(1024 * 1024 * 2);
  bf16* Wmab = (bf16*)alloc(256 * 1024 * 2);
  bf16* Wmpb = (bf16*)alloc(1024 * 512 * 2);
  bf16* mvTb = (bf16*)alloc(512 * 256 * 2);
  bf16* Qb   = (bf16*)alloc(MS_ * 1024 * 2);
  bf16* Kb   = (bf16*)alloc(MS_ * 1024 * 2);
  bf16* Vtb  = (bf16*)alloc(MS_ * 1024 * 2);  // [B][H][S]
  bf16* AO   = (bf16*)alloc(MS_ * 1024 * 2);
  float* MSc = (float*)alloc(MS_ * 256 * 4);
  bf16* MP   = (bf16*)alloc(MS_ * 256 * 2);
  bf16* MO   = (bf16*)alloc(MS_ * 512 * 2);
  bf16* CB   = (bf16*)alloc(MS_ * 1024 * 2);

  // converts (grid = n/1024, all sizes are multiples of 1024)
  f32_to_bf16<<<4096, 256, 0, stream>>>(X, Xb);
  f32_to_bf16<<<1024, 256, 0, stream>>>(Wq, Wqb);
  f32_to_bf16<<<1024, 256, 0, stream>>>(Wk, Wkb);
  f32_to_bf16<<<1024, 256, 0, stream>>>(Wv, Wvb);
  f32_to_bf16<<<1024, 256, 0, stream>>>(Wo, Wob);
  f32_to_bf16<<<256, 256, 0, stream>>>(Wma, Wmab);
  f32_to_bf16<<<512, 256, 0, stream>>>(Wmp, Wmpb);
  mv_transpose<<<512, 256, 0, stream>>>(mv, mvTb);

  // projections
  gemm_bt<bf16, false, false><<<dim3(8, 32), 256, 0, stream>>>(Xb, Wqb, bq, nullptr, Qb, 4096, 1024, 1024, 1.0f);
  gemm_bt<bf16, false, false><<<dim3(8, 32), 256, 0, stream>>>(Xb, Wkb, bk, nullptr, Kb, 4096, 1024, 1024, 1.0f);
  gemm_bt<bf16, false, true ><<<dim3(8, 32), 256, 0, stream>>>(Xb, Wvb, bv, nullptr, Vtb, 4096, 1024, 1024, 1.0f);

  // attention
  attn_fwd<<<dim3(16, 16, 2), 256, 0, stream>>>(Qb, Kb, Vtb, mask, AO);

  // memory path
  gemm_bt<float, false, false><<<dim3(2, 32), 256, 0, stream>>>(Xb, Wmab, bma, nullptr, MSc, 4096, 256, 1024, 1.0f);
  softmax_rows256<<<1024, 256, 0, stream>>>(MSc, MP);
  gemm_bt<bf16, false, false><<<dim3(4, 32), 256, 0, stream>>>(MP, mvTb, nullptr, nullptr, MO, 4096, 512, 256, 1.0f);
  // combined = attn_out + 0.3*(mem_out @ Wmp^T + bmp)
  gemm_bt<bf16, true, false><<<dim3(8, 32), 256, 0, stream>>>(MO, Wmpb, bmp, AO, CB, 4096, 1024, 512, 0.3f);
  // final projection -> fp32 out
  gemm_bt<float, false, false><<<dim3(8, 32), 256, 0, stream>>>(CB, Wob, bo, nullptr, (float*)d_out, 4096, 1024, 1024, 1.0f);
}

// Round 2
// 235.523 us; speedup vs baseline: 1.3348x; 1.3348x over previous
//
#include <hip/hip_runtime.h>

typedef __bf16 bf16;
typedef __bf16 bf16x8 __attribute__((ext_vector_type(8)));
typedef __bf16 bf16x4 __attribute__((ext_vector_type(4)));
typedef float  f32x4  __attribute__((ext_vector_type(4)));
typedef unsigned long long uptr;

#define MFMA16(a, b, c) __builtin_amdgcn_mfma_f32_16x16x32_bf16((a), (b), (c), 0, 0, 0)

// async global->LDS, 16B per lane. LDS dest is wave-uniform base + lane*16 (HW).
__device__ __forceinline__ void gl_lds16(const void* g, void* l) {
  __builtin_amdgcn_global_load_lds(
      (__attribute__((address_space(1))) void*)(uptr)(g),
      (__attribute__((address_space(3))) void*)(uptr)(l),
      16, 0, 0);
}

// ---------------------------------------------------------------------------
// fp32 -> bf16 elementwise convert (n must be a multiple of 1024)
__global__ __launch_bounds__(256) void f32_to_bf16(const float* __restrict__ in,
                                                   bf16* __restrict__ out) {
  const long i = ((long)blockIdx.x * 256 + threadIdx.x) * 4;
  const float4 v = *(const float4*)(in + i);
  bf16x4 o = {(bf16)v.x, (bf16)v.y, (bf16)v.z, (bf16)v.w};
  *(bf16x4*)(out + i) = o;
}

// memory_values [256][512] fp32 -> mvT [512][256] bf16
__global__ __launch_bounds__(256) void mv_transpose(const float* __restrict__ mv,
                                                    bf16* __restrict__ mvT) {
  const int d = blockIdx.x;   // 0..511
  const int m = threadIdx.x;  // 0..255
  mvT[(long)d * 256 + m] = (bf16)mv[(long)m * 512 + d];
}

// row softmax over 256 cols, fp32 in, bf16 out. one wave per row.
__global__ __launch_bounds__(256) void softmax_rows256(const float* __restrict__ in,
                                                       bf16* __restrict__ out) {
  const int w = threadIdx.x >> 6, l = threadIdx.x & 63;
  const long row = (long)blockIdx.x * 4 + w;
  const float4 v = *(const float4*)(in + row * 256 + l * 4);
  float mx = fmaxf(fmaxf(v.x, v.y), fmaxf(v.z, v.w));
  mx = fmaxf(mx, __shfl_xor(mx, 1, 64));
  mx = fmaxf(mx, __shfl_xor(mx, 2, 64));
  mx = fmaxf(mx, __shfl_xor(mx, 4, 64));
  mx = fmaxf(mx, __shfl_xor(mx, 8, 64));
  mx = fmaxf(mx, __shfl_xor(mx, 16, 64));
  mx = fmaxf(mx, __shfl_xor(mx, 32, 64));
  const float e0 = __expf(v.x - mx), e1 = __expf(v.y - mx);
  const float e2 = __expf(v.z - mx), e3 = __expf(v.w - mx);
  float sm = e0 + e1 + e2 + e3;
  sm += __shfl_xor(sm, 1, 64);
  sm += __shfl_xor(sm, 2, 64);
  sm += __shfl_xor(sm, 4, 64);
  sm += __shfl_xor(sm, 8, 64);
  sm += __shfl_xor(sm, 16, 64);
  sm += __shfl_xor(sm, 32, 64);
  const float inv = 1.0f / sm;
  bf16x4 o = {(bf16)(e0 * inv), (bf16)(e1 * inv), (bf16)(e2 * inv), (bf16)(e3 * inv)};
  *(bf16x4*)(out + row * 256 + l * 4) = o;
}

// ---------------------------------------------------------------------------
// C[M][N] = (A[M][K] @ B[N][K]^T + bias)*alpha (+ add)
// 128x64 tile, BK=64, 4 waves (each 32 rows x 64 cols), double-buffered LDS
// with prefetch-next-before-compute (T3 minimum 2-phase).
// TRANS_OUT: write C transposed per batch: C[(m/2048)*N + n][*2048 + m%2048]
template <typename OutT, bool HAS_ADD, bool TRANS_OUT>
__global__ __launch_bounds__(256, 3) void gemm_bt(
    const bf16* __restrict__ A, const bf16* __restrict__ B,
    const float* __restrict__ bias, const bf16* __restrict__ addsrc,
    OutT* __restrict__ C, int M, int N, int K, float alpha) {
  __shared__ bf16 lA[2][128 * 64];
  __shared__ bf16 lB[2][64 * 64];
  const int tid = threadIdx.x;
  const int w = tid >> 6, l = tid & 63;
  const int hi = l >> 4, lo = l & 15;
  const int m0 = blockIdx.y * 128, n0 = blockIdx.x * 64;
  const int wm = w * 32;

  // staging: wave w fills A rows [w*32,+32) (4 insts) and B rows [w*16,+16) (2).
  const int sr8 = l >> 3;          // 0..7 row within 8-row chunk
  const int sc = (l & 7) * 8;      // element offset within row
  const long aRow = (long)(m0 + wm + sr8);
  const long bRow = (long)(n0 + w * 16 + sr8);

  auto stage = [&](int p, int k0) {
#pragma unroll
    for (int j = 0; j < 4; ++j)
      gl_lds16(A + (aRow + 8 * j) * K + k0 + sc, (char*)lA[p] + (wm + 8 * j) * 128);
#pragma unroll
    for (int j = 0; j < 2; ++j)
      gl_lds16(B + (bRow + 8 * j) * K + k0 + sc, (char*)lB[p] + (w * 16 + 8 * j) * 128);
  };

  f32x4 acc[2][4] = {};
  stage(0, 0);
  __syncthreads();
  const int nt = K >> 6;

  for (int t = 0; t < nt; ++t) {
    const int p = t & 1;
    if (t + 1 < nt) stage(p ^ 1, (t + 1) << 6);
#pragma unroll
    for (int kk = 0; kk < 2; ++kk) {
      bf16x8 af[2], bfr[4];
#pragma unroll
      for (int mi = 0; mi < 2; ++mi)
        af[mi] = *(const bf16x8*)((const char*)lA[p] + (wm + mi * 16 + lo) * 128 + kk * 64 + hi * 16);
#pragma unroll
      for (int ni = 0; ni < 4; ++ni)
        bfr[ni] = *(const bf16x8*)((const char*)lB[p] + (ni * 16 + lo) * 128 + kk * 64 + hi * 16);
      __builtin_amdgcn_s_setprio(1);
#pragma unroll
      for (int mi = 0; mi < 2; ++mi)
#pragma unroll
        for (int ni = 0; ni < 4; ++ni)
          acc[mi][ni] = MFMA16(af[mi], bfr[ni], acc[mi][ni]);
      __builtin_amdgcn_s_setprio(0);
    }
    __syncthreads();
  }

#pragma unroll
  for (int ni = 0; ni < 4; ++ni) {
    const int col = n0 + ni * 16 + lo;
    const float bv = bias ? bias[col] : 0.0f;
#pragma unroll
    for (int mi = 0; mi < 2; ++mi) {
      const int mrow = m0 + wm + mi * 16 + hi * 4;
#pragma unroll
      for (int r = 0; r < 4; ++r) {
        const long row = mrow + r;
        float v = (acc[mi][ni][r] + bv) * alpha;
        if (HAS_ADD) v += (float)addsrc[row * N + col];
        if (TRANS_OUT) {
          const long bb = row >> 11, ss = row & 2047;
          C[(bb * N + col) * 2048 + ss] = (OutT)v;
        } else {
          C[row * (long)N + col] = (OutT)v;
        }
      }
    }
  }
}

// ---------------------------------------------------------------------------
// Flash attention. Q,K: [B*S][H] bf16 (head h at cols h*64..). Vt: [B][H][S] bf16.
// Block: 256 thr / 4 waves; 64 Q rows per block (16 per wave); 64-key tiles.
// K/V double-buffered + prefetched; softmax in exp2 domain with defer-max.
__global__ __launch_bounds__(256, 4) void attn_fwd(
    const bf16* __restrict__ Q, const bf16* __restrict__ Km,
    const bf16* __restrict__ Vt, const float* __restrict__ mask,
    bf16* __restrict__ AO) {
  __shared__ bf16 lK[2][64 * 64];   // [key][d], XOR-swizzled chunks
  __shared__ bf16 lV[2][64 * 64];   // [d][key]
  __shared__ bf16 lP[4][16 * 64];   // per-wave P [q][k], swizzled
  const int tid = threadIdx.x, w = tid >> 6, l = tid & 63;
  const int hi = l >> 4, lo = l & 15;
  const int b = blockIdx.z, h = blockIdx.y, q0 = blockIdx.x * 64;
  const long S = 2048, Hh = 1024;
  const float SCALE2 = 0.125f * 1.44269504f;  // fold log2(e): exp2 domain

  // Q fragments (A-frag: row=l%16, k=(l/16)*8+j), held in registers
  bf16x8 qf[2];
#pragma unroll
  for (int ds = 0; ds < 2; ++ds) {
    const long row = (long)b * S + q0 + w * 16 + lo;
    qf[ds] = *(const bf16x8*)(Q + row * Hh + h * 64 + ds * 32 + hi * 8);
  }

  f32x4 o[4] = {};
  float mrun[4], lrun[4];
#pragma unroll
  for (int r = 0; r < 4; ++r) { mrun[r] = -1e30f; lrun[r] = 0.0f; }

  // staging: wave w covers tile rows [w*16, w*16+16), 2 insts of 8 rows each.
  // swizzled source chunk: (l&7) ^ (l>>3)  (row&7 == l>>3 since bases 8-aligned)
  const int swr = w * 16 + (l >> 3);
  const int swc = ((l & 7) ^ (l >> 3)) * 8;

  auto stage = [&](int p, int k0) {
#pragma unroll
    for (int j = 0; j < 2; ++j) {
      gl_lds16(Km + ((long)b * S + k0 + swr + 8 * j) * Hh + h * 64 + swc,
               (char*)lK[p] + (w * 16 + 8 * j) * 128);
      gl_lds16(Vt + ((long)b * Hh + h * 64 + swr + 8 * j) * S + k0 + swc,
               (char*)lV[p] + (w * 16 + 8 * j) * 128);
    }
  };

  stage(0, 0);
  __syncthreads();

  for (int t = 0; t < 32; ++t) {
    const int p = t & 1, k0 = t * 64;
    if (t < 31) stage(p ^ 1, k0 + 64);

    float madd[4];
#pragma unroll
    for (int kf = 0; kf < 4; ++kf)
      madd[kf] = mask[(long)b * S + k0 + kf * 16 + lo] * (-1.44269504e9f);

    // S2 = (Q K^T) * scale * log2e + mask2
    f32x4 s[4] = {};
    __builtin_amdgcn_s_setprio(1);
#pragma unroll
    for (int kf = 0; kf < 4; ++kf) {
      const int krow = kf * 16 + lo;
#pragma unroll
      for (int ds = 0; ds < 2; ++ds) {
        const int cb = ((ds * 4 + hi) ^ (krow & 7)) * 16;
        const bf16x8 kb = *(const bf16x8*)((const char*)lK[p] + krow * 128 + cb);
        s[kf] = MFMA16(qf[ds], kb, s[kf]);
      }
    }
    __builtin_amdgcn_s_setprio(0);
#pragma unroll
    for (int kf = 0; kf < 4; ++kf)
      s[kf] = s[kf] * SCALE2 + madd[kf];

    // online softmax in exp2 domain; row r (q=hi*4+r) spread over 16 lo-lanes
    float mx[4], f[4], rs[4];
#pragma unroll
    for (int r = 0; r < 4; ++r)
      mx[r] = fmaxf(fmaxf(s[0][r], s[1][r]), fmaxf(s[2][r], s[3][r]));
#pragma unroll
    for (int r = 0; r < 4; ++r) {
      mx[r] = fmaxf(mx[r], __shfl_xor(mx[r], 1, 64));
      mx[r] = fmaxf(mx[r], __shfl_xor(mx[r], 2, 64));
      mx[r] = fmaxf(mx[r], __shfl_xor(mx[r], 4, 64));
      mx[r] = fmaxf(mx[r], __shfl_xor(mx[r], 8, 64));
    }
    // defer-max (T13): only rescale when some row's max grew by > 8 (exp2 dom)
    const bool need = (mx[0] > mrun[0] + 8.0f) || (mx[1] > mrun[1] + 8.0f) ||
                      (mx[2] > mrun[2] + 8.0f) || (mx[3] > mrun[3] + 8.0f);
    const bool resc = __any(need);
    if (resc) {
#pragma unroll
      for (int r = 0; r < 4; ++r) {
        const float mn = fmaxf(mrun[r], mx[r]);
        f[r] = __builtin_amdgcn_exp2f(mrun[r] - mn);
        mrun[r] = mn;
      }
    }
#pragma unroll
    for (int kf = 0; kf < 4; ++kf)
#pragma unroll
      for (int r = 0; r < 4; ++r)
        s[kf][r] = __builtin_amdgcn_exp2f(s[kf][r] - mrun[r]);
#pragma unroll
    for (int r = 0; r < 4; ++r) {
      rs[r] = s[0][r] + s[1][r] + s[2][r] + s[3][r];
      rs[r] += __shfl_xor(rs[r], 1, 64);
      rs[r] += __shfl_xor(rs[r], 2, 64);
      rs[r] += __shfl_xor(rs[r], 4, 64);
      rs[r] += __shfl_xor(rs[r], 8, 64);
    }
    if (resc) {
#pragma unroll
      for (int r = 0; r < 4; ++r) lrun[r] = lrun[r] * f[r] + rs[r];
#pragma unroll
      for (int df = 0; df < 4; ++df)
#pragma unroll
        for (int r = 0; r < 4; ++r) o[df][r] *= f[r];
    } else {
#pragma unroll
      for (int r = 0; r < 4; ++r) lrun[r] += rs[r];
    }

    // P (bf16) -> wave-private LDS, XOR-swizzled rows
#pragma unroll
    for (int kf = 0; kf < 4; ++kf)
#pragma unroll
      for (int r = 0; r < 4; ++r) {
        const int qrow = hi * 4 + r;
        const int byt = qrow * 128 + (((kf * 16 + lo) * 2) ^ ((qrow & 7) << 4));
        *(bf16*)((char*)lP[w] + byt) = (bf16)s[kf][r];
      }

    // O += P V
    __builtin_amdgcn_s_setprio(1);
#pragma unroll
    for (int kk = 0; kk < 2; ++kk) {
      const int cb = ((kk * 4 + hi) ^ (lo & 7)) * 16;
      const bf16x8 pa = *(const bf16x8*)((const char*)lP[w] + lo * 128 + cb);
#pragma unroll
      for (int df = 0; df < 4; ++df) {
        const int vrow = df * 16 + lo;
        const int cvb = ((kk * 4 + hi) ^ (vrow & 7)) * 16;
        const bf16x8 vb = *(const bf16x8*)((const char*)lV[p] + vrow * 128 + cvb);
        o[df] = MFMA16(pa, vb, o[df]);
      }
    }
    __builtin_amdgcn_s_setprio(0);
    __syncthreads();
  }

#pragma unroll
  for (int df = 0; df < 4; ++df)
#pragma unroll
    for (int r = 0; r < 4; ++r) {
      const long q = (long)b * S + q0 + w * 16 + hi * 4 + r;
      AO[q * Hh + h * 64 + df * 16 + lo] = (bf16)(o[df][r] / lrun[r]);
    }
}

// ---------------------------------------------------------------------------
extern "C" void kernel_launch(void* const* d_in, const int* in_sizes, int n_in,
                              void* d_out, int out_size, void* d_ws, size_t ws_size,
                              hipStream_t stream) {
  const float* X    = (const float*)d_in[0];
  const float* mask = (const float*)d_in[1];
  const float* Wq   = (const float*)d_in[2];  const float* bq  = (const float*)d_in[3];
  const float* Wk   = (const float*)d_in[4];  const float* bk  = (const float*)d_in[5];
  const float* Wv   = (const float*)d_in[6];  const float* bv  = (const float*)d_in[7];
  const float* Wo   = (const float*)d_in[8];  const float* bo  = (const float*)d_in[9];
  const float* mv   = (const float*)d_in[10];
  const float* Wmp  = (const float*)d_in[11]; const float* bmp = (const float*)d_in[12];
  const float* Wma  = (const float*)d_in[13]; const float* bma = (const float*)d_in[14];

  char* ws = (char*)d_ws;
  size_t off = 0;
  auto alloc = [&](size_t bytes) -> void* {
    void* p = ws + off;
    off += (bytes + 255) & ~(size_t)255;
    return p;
  };
  const long MS_ = 4096;  // B*S rows
  bf16* Xb   = (bf16*)alloc(MS_ * 1024 * 2);
  bf16* Wqb  = (bf16*)alloc(1024 * 1024 * 2);
  bf16* Wkb  = (bf16*)alloc(1024 * 1024 * 2);
  bf16* Wvb  = (bf16*)alloc(1024 * 1024 * 2);
  bf16* Wob  = (bf16*)alloc(1024 * 1024 * 2);
  bf16* Wmab = (bf16*)alloc(256 * 1024 * 2);
  bf16* Wmpb = (bf16*)alloc(1024 * 512 * 2);
  bf16* mvTb = (bf16*)alloc(512 * 256 * 2);
  bf16* Qb   = (bf16*)alloc(MS_ * 1024 * 2);
  bf16* Kb   = (bf16*)alloc(MS_ * 1024 * 2);
  bf16* Vtb  = (bf16*)alloc(MS_ * 1024 * 2);  // [B][H][S]
  bf16* AO   = (bf16*)alloc(MS_ * 1024 * 2);
  float* MSc = (float*)alloc(MS_ * 256 * 4);
  bf16* MP   = (bf16*)alloc(MS_ * 256 * 2);
  bf16* MO   = (bf16*)alloc(MS_ * 512 * 2);
  bf16* CB   = (bf16*)alloc(MS_ * 1024 * 2);

  // converts (grid = n/1024, all sizes are multiples of 1024)
  f32_to_bf16<<<4096, 256, 0, stream>>>(X, Xb);
  f32_to_bf16<<<1024, 256, 0, stream>>>(Wq, Wqb);
  f32_to_bf16<<<1024, 256, 0, stream>>>(Wk, Wkb);
  f32_to_bf16<<<1024, 256, 0, stream>>>(Wv, Wvb);
  f32_to_bf16<<<1024, 256, 0, stream>>>(Wo, Wob);
  f32_to_bf16<<<256, 256, 0, stream>>>(Wma, Wmab);
  f32_to_bf16<<<512, 256, 0, stream>>>(Wmp, Wmpb);
  mv_transpose<<<512, 256, 0, stream>>>(mv, mvTb);

  // projections (tiles: 128 rows x 64 cols)
  gemm_bt<bf16, false, false><<<dim3(16, 32), 256, 0, stream>>>(Xb, Wqb, bq, nullptr, Qb, 4096, 1024, 1024, 1.0f);
  gemm_bt<bf16, false, false><<<dim3(16, 32), 256, 0, stream>>>(Xb, Wkb, bk, nullptr, Kb, 4096, 1024, 1024, 1.0f);
  gemm_bt<bf16, false, true ><<<dim3(16, 32), 256, 0, stream>>>(Xb, Wvb, bv, nullptr, Vtb, 4096, 1024, 1024, 1.0f);

  // attention (64 q-rows per block)
  attn_fwd<<<dim3(32, 16, 2), 256, 0, stream>>>(Qb, Kb, Vtb, mask, AO);

  // memory path
  gemm_bt<float, false, false><<<dim3(4, 32), 256, 0, stream>>>(Xb, Wmab, bma, nullptr, MSc, 4096, 256, 1024, 1.0f);
  softmax_rows256<<<1024, 256, 0, stream>>>(MSc, MP);
  gemm_bt<bf16, false, false><<<dim3(8, 32), 256, 0, stream>>>(MP, mvTb, nullptr, nullptr, MO, 4096, 512, 256, 1.0f);
  // combined = attn_out + 0.3*(mem_out @ Wmp^T + bmp)
  gemm_bt<bf16, true, false><<<dim3(16, 32), 256, 0, stream>>>(MO, Wmpb, bmp, AO, CB, 4096, 1024, 512, 0.3f);
  // final projection -> fp32 out
  gemm_bt<float, false, false><<<dim3(16, 32), 256, 0, stream>>>(CB, Wob, bo, nullptr, (float*)d_out, 4096, 1024, 1024, 1.0f);
}

// Round 3
// 167.558 us; speedup vs baseline: 1.8763x; 1.4056x over previous
//
#include <hip/hip_runtime.h>

typedef __bf16 bf16;
typedef __bf16 bf16x8 __attribute__((ext_vector_type(8)));
typedef __bf16 bf16x4 __attribute__((ext_vector_type(4)));
typedef float  f32x4  __attribute__((ext_vector_type(4)));
typedef float  f32x16 __attribute__((ext_vector_type(16)));
typedef unsigned u32x2 __attribute__((ext_vector_type(2)));
typedef unsigned u32x4 __attribute__((ext_vector_type(4)));
typedef unsigned long long uptr;

#define MFMA16(a, b, c) __builtin_amdgcn_mfma_f32_16x16x32_bf16((a), (b), (c), 0, 0, 0)
#define MFMA32(a, b, c) __builtin_amdgcn_mfma_f32_32x32x16_bf16((a), (b), (c), 0, 0, 0)

__device__ __forceinline__ void gl_lds16(const void* g, void* l) {
  __builtin_amdgcn_global_load_lds(
      (__attribute__((address_space(1))) void*)(uptr)(g),
      (__attribute__((address_space(3))) void*)(uptr)(l),
      16, 0, 0);
}
__device__ __forceinline__ void gl_lds4(const void* g, void* l) {
  __builtin_amdgcn_global_load_lds(
      (__attribute__((address_space(1))) void*)(uptr)(g),
      (__attribute__((address_space(3))) void*)(uptr)(l),
      4, 0, 0);
}
__device__ __forceinline__ unsigned cvtpk_bf16(float lo, float hi) {
  unsigned r;
  asm("v_cvt_pk_bf16_f32 %0, %1, %2" : "=v"(r) : "v"(lo), "v"(hi));
  return r;
}

// ---------------------------------------------------------------------------
// One fused prep kernel: f32->bf16 converts, QKV weight/bias concat, mask
// premultiply (exp2-domain), memory_values transpose.
__global__ __launch_bounds__(256) void fused_prep(
    const float* __restrict__ X, const float* __restrict__ Wq,
    const float* __restrict__ Wk, const float* __restrict__ Wv,
    const float* __restrict__ Wo, const float* __restrict__ Wma,
    const float* __restrict__ Wmp, const float* __restrict__ mask,
    const float* __restrict__ bq, const float* __restrict__ bk,
    const float* __restrict__ bv, const float* __restrict__ mv,
    bf16* __restrict__ Xb, bf16* __restrict__ Wqkvb, bf16* __restrict__ Wob,
    bf16* __restrict__ Wmab, bf16* __restrict__ Wmpb,
    float* __restrict__ M2, float* __restrict__ bqkv, bf16* __restrict__ mvTb) {
  const int bid = blockIdx.x, t = threadIdx.x;
  auto cvt = [&](const float* src, bf16* dst, int blk) {
    const long i = ((long)blk * 256 + t) * 4;
    const float4 v = *(const float4*)(src + i);
    bf16x4 o = {(bf16)v.x, (bf16)v.y, (bf16)v.z, (bf16)v.w};
    *(bf16x4*)(dst + i) = o;
  };
  if (bid < 4096) cvt(X, Xb, bid);
  else if (bid < 5120) cvt(Wq, Wqkvb, bid - 4096);
  else if (bid < 6144) cvt(Wk, Wqkvb + 1024 * 1024, bid - 5120);
  else if (bid < 7168) cvt(Wv, Wqkvb + 2 * 1024 * 1024, bid - 6144);
  else if (bid < 8192) cvt(Wo, Wob, bid - 7168);
  else if (bid < 8448) cvt(Wma, Wmab, bid - 8192);
  else if (bid < 8960) cvt(Wmp, Wmpb, bid - 8448);
  else if (bid < 8964) {  // mask -> exp2-domain additive
    const long i = ((long)(bid - 8960) * 256 + t) * 4;
    const float4 v = *(const float4*)(mask + i);
    float4 o = {v.x * -1.44269504e9f, v.y * -1.44269504e9f,
                v.z * -1.44269504e9f, v.w * -1.44269504e9f};
    *(float4*)(M2 + i) = o;
  } else if (bid < 8967) {  // bias concat
    const int s = bid - 8964;
    const float* src = s == 0 ? bq : (s == 1 ? bk : bv);
    *(float4*)(bqkv + s * 1024 + t * 4) = *(const float4*)(src + t * 4);
  } else {  // memory_values transpose [256][512] -> [512][256] bf16
    const int d = bid - 8967;
    mvTb[(long)d * 256 + t] = (bf16)mv[(long)t * 512 + d];
  }
}

// row softmax over 256 cols, fp32 in, bf16 out. one wave per row.
__global__ __launch_bounds__(256) void softmax_rows256(const float* __restrict__ in,
                                                       bf16* __restrict__ out) {
  const int w = threadIdx.x >> 6, l = threadIdx.x & 63;
  const long row = (long)blockIdx.x * 4 + w;
  const float4 v = *(const float4*)(in + row * 256 + l * 4);
  float mx = fmaxf(fmaxf(v.x, v.y), fmaxf(v.z, v.w));
  mx = fmaxf(mx, __shfl_xor(mx, 1, 64));
  mx = fmaxf(mx, __shfl_xor(mx, 2, 64));
  mx = fmaxf(mx, __shfl_xor(mx, 4, 64));
  mx = fmaxf(mx, __shfl_xor(mx, 8, 64));
  mx = fmaxf(mx, __shfl_xor(mx, 16, 64));
  mx = fmaxf(mx, __shfl_xor(mx, 32, 64));
  const float e0 = __expf(v.x - mx), e1 = __expf(v.y - mx);
  const float e2 = __expf(v.z - mx), e3 = __expf(v.w - mx);
  float sm = e0 + e1 + e2 + e3;
  sm += __shfl_xor(sm, 1, 64);
  sm += __shfl_xor(sm, 2, 64);
  sm += __shfl_xor(sm, 4, 64);
  sm += __shfl_xor(sm, 8, 64);
  sm += __shfl_xor(sm, 16, 64);
  sm += __shfl_xor(sm, 32, 64);
  const float inv = 1.0f / sm;
  bf16x4 o = {(bf16)(e0 * inv), (bf16)(e1 * inv), (bf16)(e2 * inv), (bf16)(e3 * inv)};
  *(bf16x4*)(out + row * 256 + l * 4) = o;
}

// ---------------------------------------------------------------------------
// Generic GEMM: C[M][N] = (A[M][K] @ B[N][K]^T + bias)*alpha (+ add)
// 128x64 tile, BK=64, 4 waves, double-buffered LDS with prefetch.
template <typename OutT, bool HAS_ADD>
__global__ __launch_bounds__(256, 3) void gemm_bt(
    const bf16* __restrict__ A, const bf16* __restrict__ B,
    const float* __restrict__ bias, const bf16* __restrict__ addsrc,
    OutT* __restrict__ C, int M, int N, int K, float alpha) {
  __shared__ bf16 lA[2][128 * 64];
  __shared__ bf16 lB[2][64 * 64];
  const int tid = threadIdx.x;
  const int w = tid >> 6, l = tid & 63;
  const int hi = l >> 4, lo = l & 15;
  const int m0 = blockIdx.y * 128, n0 = blockIdx.x * 64;
  const int wm = w * 32;

  const int sr8 = l >> 3;
  const int sc = (l & 7) * 8;
  const long aRow = (long)(m0 + wm + sr8);
  const long bRow = (long)(n0 + w * 16 + sr8);

  auto stage = [&](int p, int k0) {
#pragma unroll
    for (int j = 0; j < 4; ++j)
      gl_lds16(A + (aRow + 8 * j) * K + k0 + sc, (char*)lA[p] + (wm + 8 * j) * 128);
#pragma unroll
    for (int j = 0; j < 2; ++j)
      gl_lds16(B + (bRow + 8 * j) * K + k0 + sc, (char*)lB[p] + (w * 16 + 8 * j) * 128);
  };

  f32x4 acc[2][4] = {};
  stage(0, 0);
  __syncthreads();
  const int nt = K >> 6;

  for (int t = 0; t < nt; ++t) {
    const int p = t & 1;
    if (t + 1 < nt) stage(p ^ 1, (t + 1) << 6);
#pragma unroll
    for (int kk = 0; kk < 2; ++kk) {
      bf16x8 af[2], bfr[4];
#pragma unroll
      for (int mi = 0; mi < 2; ++mi)
        af[mi] = *(const bf16x8*)((const char*)lA[p] + (wm + mi * 16 + lo) * 128 + kk * 64 + hi * 16);
#pragma unroll
      for (int ni = 0; ni < 4; ++ni)
        bfr[ni] = *(const bf16x8*)((const char*)lB[p] + (ni * 16 + lo) * 128 + kk * 64 + hi * 16);
      __builtin_amdgcn_s_setprio(1);
#pragma unroll
      for (int mi = 0; mi < 2; ++mi)
#pragma unroll
        for (int ni = 0; ni < 4; ++ni)
          acc[mi][ni] = MFMA16(af[mi], bfr[ni], acc[mi][ni]);
      __builtin_amdgcn_s_setprio(0);
    }
    __syncthreads();
  }

#pragma unroll
  for (int ni = 0; ni < 4; ++ni) {
    const int col = n0 + ni * 16 + lo;
    const float bv = bias ? bias[col] : 0.0f;
#pragma unroll
    for (int mi = 0; mi < 2; ++mi) {
      const int mrow = m0 + wm + mi * 16 + hi * 4;
#pragma unroll
      for (int r = 0; r < 4; ++r) {
        const long row = mrow + r;
        float v = (acc[mi][ni][r] + bv) * alpha;
        if (HAS_ADD) v += (float)addsrc[row * N + col];
        C[row * (long)N + col] = (OutT)v;
      }
    }
  }
}

// Fused QKV projection: A[4096][1024] @ Wqkv[3072][1024]^T + bqkv.
// cols 0..1023 -> Q, 1024..2047 -> K, 2048..3071 -> V transposed [B][h*64+d][S].
__global__ __launch_bounds__(256, 3) void gemm_qkv(
    const bf16* __restrict__ A, const bf16* __restrict__ B,
    const float* __restrict__ bias, bf16* __restrict__ Qo,
    bf16* __restrict__ Ko, bf16* __restrict__ Vto) {
  const int K = 1024, N = 3072;
  __shared__ bf16 lA[2][128 * 64];
  __shared__ bf16 lB[2][64 * 64];
  const int tid = threadIdx.x;
  const int w = tid >> 6, l = tid & 63;
  const int hi = l >> 4, lo = l & 15;
  const int m0 = blockIdx.y * 128, n0 = blockIdx.x * 64;
  const int wm = w * 32;
  const int sr8 = l >> 3;
  const int sc = (l & 7) * 8;
  const long aRow = (long)(m0 + wm + sr8);
  const long bRow = (long)(n0 + w * 16 + sr8);

  auto stage = [&](int p, int k0) {
#pragma unroll
    for (int j = 0; j < 4; ++j)
      gl_lds16(A + (aRow + 8 * j) * K + k0 + sc, (char*)lA[p] + (wm + 8 * j) * 128);
#pragma unroll
    for (int j = 0; j < 2; ++j)
      gl_lds16(B + (bRow + 8 * j) * K + k0 + sc, (char*)lB[p] + (w * 16 + 8 * j) * 128);
  };

  f32x4 acc[2][4] = {};
  stage(0, 0);
  __syncthreads();

  for (int t = 0; t < 16; ++t) {
    const int p = t & 1;
    if (t < 15) stage(p ^ 1, (t + 1) << 6);
#pragma unroll
    for (int kk = 0; kk < 2; ++kk) {
      bf16x8 af[2], bfr[4];
#pragma unroll
      for (int mi = 0; mi < 2; ++mi)
        af[mi] = *(const bf16x8*)((const char*)lA[p] + (wm + mi * 16 + lo) * 128 + kk * 64 + hi * 16);
#pragma unroll
      for (int ni = 0; ni < 4; ++ni)
        bfr[ni] = *(const bf16x8*)((const char*)lB[p] + (ni * 16 + lo) * 128 + kk * 64 + hi * 16);
      __builtin_amdgcn_s_setprio(1);
#pragma unroll
      for (int mi = 0; mi < 2; ++mi)
#pragma unroll
        for (int ni = 0; ni < 4; ++ni)
          acc[mi][ni] = MFMA16(af[mi], bfr[ni], acc[mi][ni]);
      __builtin_amdgcn_s_setprio(0);
    }
    __syncthreads();
  }

  const int region = n0 >> 10;  // 0=Q 1=K 2=V (block never straddles)
#pragma unroll
  for (int ni = 0; ni < 4; ++ni) {
    const int col = n0 + ni * 16 + lo;
    const float bv = bias[col];
#pragma unroll
    for (int mi = 0; mi < 2; ++mi) {
      const int mrow = m0 + wm + mi * 16 + hi * 4;
#pragma unroll
      for (int r = 0; r < 4; ++r) {
        const long row = mrow + r;
        const float v = acc[mi][ni][r] + bv;
        if (region == 0) {
          Qo[row * 1024 + col] = (bf16)v;
        } else if (region == 1) {
          Ko[row * 1024 + (col - 1024)] = (bf16)v;
        } else {
          const long bb = row >> 11, ss = row & 2047;
          Vto[(bb * 1024 + (col - 2048)) * 2048 + ss] = (bf16)v;
        }
      }
    }
  }
}

// ---------------------------------------------------------------------------
// Flash attention, swapped-QK^T 32x32 structure (m214-style).
// Q,K: [B*S][1024] bf16; Vt: [B][1024=h*64+d][S] bf16; M2: mask*(-1e9*log2e).
// 4 waves x 32 q-rows = 128 q/block; 64-key tiles, K/V dbuf + XOR swizzle.
// Lane owns P-row half for q = lane&31: in-lane softmax + 1 shfl_xor(32).
// P -> A-frag via cvt_pk_bf16 + permlane32_swap (T12). Defer-max (T13).
__global__ __launch_bounds__(256, 2) void attn_fwd(
    const bf16* __restrict__ Q, const bf16* __restrict__ Km,
    const bf16* __restrict__ Vt, const float* __restrict__ M2,
    bf16* __restrict__ AO) {
  __shared__ bf16 lK[2][64 * 64];
  __shared__ bf16 lV[2][64 * 64];
  __shared__ alignas(16) float lM[2][64];
  const int tid = threadIdx.x, w = tid >> 6, l = tid & 63;
  const int q31 = l & 31, h32 = l >> 5;
  const int b = blockIdx.z, hh = blockIdx.y, q0 = blockIdx.x * 128;
  const long S = 2048, H = 1024;
  const float SCALE2 = 0.125f * 1.44269504f;

  // Q as B-operand: col=lane&31=q, k=(lane>>5)*8+j; 4 slices of 16 over d=64
  bf16x8 qf[4];
  const long qrow = (long)b * S + q0 + w * 32 + q31;
#pragma unroll
  for (int sl = 0; sl < 4; ++sl)
    qf[sl] = *(const bf16x8*)(Q + qrow * H + hh * 64 + sl * 16 + h32 * 8);

  f32x16 o0 = {}, o1 = {};
  float mrun = -1e30f, lrun = 0.0f;

  const int swr = w * 16 + (l >> 3);
  const int swc = ((l & 7) ^ (l >> 3)) * 8;

  auto stage = [&](int p, int k0) {
#pragma unroll
    for (int j = 0; j < 2; ++j) {
      gl_lds16(Km + ((long)b * S + k0 + swr + 8 * j) * H + hh * 64 + swc,
               (char*)lK[p] + (w * 16 + 8 * j) * 128);
      gl_lds16(Vt + ((long)b * H + hh * 64 + swr + 8 * j) * S + k0 + swc,
               (char*)lV[p] + (w * 16 + 8 * j) * 128);
    }
    if (w == 0) gl_lds4(M2 + (long)b * S + k0 + l, (char*)lM[p]);
  };

  stage(0, 0);
  __syncthreads();

  for (int t = 0; t < 32; ++t) {
    const int p = t & 1;
    if (t < 31) stage(p ^ 1, (t + 1) * 64);

    // S = K Q^T (swapped): D[key][q], q = lane&31
    f32x16 s0 = {}, s1 = {};
    __builtin_amdgcn_s_setprio(1);
#pragma unroll
    for (int sl = 0; sl < 4; ++sl) {
      const int ch = sl * 2 + h32;
      const int cx = (ch ^ (q31 & 7)) * 16;
      const bf16x8 k0f = *(const bf16x8*)((const char*)lK[p] + q31 * 128 + cx);
      const bf16x8 k1f = *(const bf16x8*)((const char*)lK[p] + (32 + q31) * 128 + cx);
      s0 = MFMA32(k0f, qf[sl], s0);
      s1 = MFMA32(k1f, qf[sl], s1);
    }
    __builtin_amdgcn_s_setprio(0);

    // scale + additive mask (exp2 domain); reg->key row = (reg&3)+8*(reg>>2)+4*h32
#pragma unroll
    for (int g = 0; g < 4; ++g) {
      const f32x4 m0 = *(const f32x4*)&lM[p][8 * g + 4 * h32];
      const f32x4 m1 = *(const f32x4*)&lM[p][32 + 8 * g + 4 * h32];
#pragma unroll
      for (int r = 0; r < 4; ++r) {
        s0[4 * g + r] = s0[4 * g + r] * SCALE2 + m0[r];
        s1[4 * g + r] = s1[4 * g + r] * SCALE2 + m1[r];
      }
    }

    // row max: in-lane tree + one cross-half shuffle
    f32x16 tm;
#pragma unroll
    for (int i = 0; i < 16; ++i) tm[i] = fmaxf(s0[i], s1[i]);
#pragma unroll
    for (int i = 0; i < 8; ++i) tm[i] = fmaxf(tm[i], tm[i + 8]);
#pragma unroll
    for (int i = 0; i < 4; ++i) tm[i] = fmaxf(tm[i], tm[i + 4]);
    float mx = fmaxf(fmaxf(tm[0], tm[1]), fmaxf(tm[2], tm[3]));
    mx = fmaxf(mx, __shfl_xor(mx, 32, 64));

    // defer-max (T13)
    if (__any(mx > mrun + 8.0f)) {
      const float mn = fmaxf(mrun, mx);
      const float f = __builtin_amdgcn_exp2f(mrun - mn);
      mrun = mn;
      lrun *= f;
      float fb[16];
#pragma unroll
      for (int reg = 0; reg < 16; ++reg)
        fb[reg] = __shfl(f, (reg & 3) + 8 * (reg >> 2) + 4 * h32, 64);
#pragma unroll
      for (int reg = 0; reg < 16; ++reg) { o0[reg] *= fb[reg]; o1[reg] *= fb[reg]; }
    }

    // P = exp2(s - m)
#pragma unroll
    for (int i = 0; i < 16; ++i) s0[i] = __builtin_amdgcn_exp2f(s0[i] - mrun);
#pragma unroll
    for (int i = 0; i < 16; ++i) s1[i] = __builtin_amdgcn_exp2f(s1[i] - mrun);

    // row sum: in-lane tree + one cross-half shuffle
    f32x16 ts;
#pragma unroll
    for (int i = 0; i < 16; ++i) ts[i] = s0[i] + s1[i];
#pragma unroll
    for (int i = 0; i < 8; ++i) ts[i] += ts[i + 8];
#pragma unroll
    for (int i = 0; i < 4; ++i) ts[i] += ts[i + 4];
    float rs = (ts[0] + ts[1]) + (ts[2] + ts[3]);
    rs += __shfl_xor(rs, 32, 64);
    lrun += rs;

    // P (C-layout f32) -> PV A-frags: cvt_pk + permlane32_swap (T12)
    bf16x8 pa[4];
#pragma unroll
    for (int ks = 0; ks < 4; ++ks) {
      const int rb = (ks & 1) * 8;
      unsigned a0, a1, b0, b1;
      if (ks < 2) {
        a0 = cvtpk_bf16(s0[rb + 0], s0[rb + 1]);
        a1 = cvtpk_bf16(s0[rb + 2], s0[rb + 3]);
        b0 = cvtpk_bf16(s0[rb + 4], s0[rb + 5]);
        b1 = cvtpk_bf16(s0[rb + 6], s0[rb + 7]);
      } else {
        a0 = cvtpk_bf16(s1[rb + 0], s1[rb + 1]);
        a1 = cvtpk_bf16(s1[rb + 2], s1[rb + 3]);
        b0 = cvtpk_bf16(s1[rb + 4], s1[rb + 5]);
        b1 = cvtpk_bf16(s1[rb + 6], s1[rb + 7]);
      }
      const u32x2 r02 = __builtin_amdgcn_permlane32_swap(a0, b0, false, false);
      const u32x2 r13 = __builtin_amdgcn_permlane32_swap(a1, b1, false, false);
      const u32x4 pw = {r02[0], r13[0], r02[1], r13[1]};
      pa[ks] = __builtin_bit_cast(bf16x8, pw);
    }

    // O += P V  (B-frag of V from lV[d][key], same XOR swizzle)
    __builtin_amdgcn_s_setprio(1);
#pragma unroll
    for (int ks = 0; ks < 4; ++ks) {
      const int ch = ks * 2 + h32;
      const int cx = (ch ^ (q31 & 7)) * 16;
      const bf16x8 v0 = *(const bf16x8*)((const char*)lV[p] + q31 * 128 + cx);
      const bf16x8 v1 = *(const bf16x8*)((const char*)lV[p] + (32 + q31) * 128 + cx);
      o0 = MFMA32(pa[ks], v0, o0);
      o1 = MFMA32(pa[ks], v1, o1);
    }
    __builtin_amdgcn_s_setprio(0);
    __syncthreads();
  }

  // epilogue: O[q][d] rows per reg; fetch 1/l per row via bpermute
  const float linv = 1.0f / lrun;
#pragma unroll
  for (int reg = 0; reg < 16; ++reg) {
    const int row = (reg & 3) + 8 * (reg >> 2) + 4 * h32;
    const float lb = __shfl(linv, row, 64);
    const long qg = (long)b * S + q0 + w * 32 + row;
    AO[qg * H + hh * 64 + q31]      = (bf16)(o0[reg] * lb);
    AO[qg * H + hh * 64 + 32 + q31] = (bf16)(o1[reg] * lb);
  }
}

// ---------------------------------------------------------------------------
extern "C" void kernel_launch(void* const* d_in, const int* in_sizes, int n_in,
                              void* d_out, int out_size, void* d_ws, size_t ws_size,
                              hipStream_t stream) {
  const float* X    = (const float*)d_in[0];
  const float* mask = (const float*)d_in[1];
  const float* Wq   = (const float*)d_in[2];  const float* bq  = (const float*)d_in[3];
  const float* Wk   = (const float*)d_in[4];  const float* bk  = (const float*)d_in[5];
  const float* Wv   = (const float*)d_in[6];  const float* bv  = (const float*)d_in[7];
  const float* Wo   = (const float*)d_in[8];  const float* bo  = (const float*)d_in[9];
  const float* mv   = (const float*)d_in[10];
  const float* Wmp  = (const float*)d_in[11]; const float* bmp = (const float*)d_in[12];
  const float* Wma  = (const float*)d_in[13]; const float* bma = (const float*)d_in[14];

  char* ws = (char*)d_ws;
  size_t off = 0;
  auto alloc = [&](size_t bytes) -> void* {
    void* p = ws + off;
    off += (bytes + 255) & ~(size_t)255;
    return p;
  };
  const long MS_ = 4096;  // B*S rows
  bf16* Xb    = (bf16*)alloc(MS_ * 1024 * 2);
  bf16* Wqkvb = (bf16*)alloc(3072L * 1024 * 2);
  bf16* Wob   = (bf16*)alloc(1024 * 1024 * 2);
  bf16* Wmab  = (bf16*)alloc(256 * 1024 * 2);
  bf16* Wmpb  = (bf16*)alloc(1024 * 512 * 2);
  bf16* mvTb  = (bf16*)alloc(512 * 256 * 2);
  float* M2   = (float*)alloc(MS_ * 4);
  float* bqkv = (float*)alloc(3072 * 4);
  bf16* Qb    = (bf16*)alloc(MS_ * 1024 * 2);
  bf16* Kb    = (bf16*)alloc(MS_ * 1024 * 2);
  bf16* Vtb   = (bf16*)alloc(MS_ * 1024 * 2);  // [B][h*64+d][S]
  bf16* AO    = (bf16*)alloc(MS_ * 1024 * 2);
  float* MSc  = (float*)alloc(MS_ * 256 * 4);
  bf16* MP    = (bf16*)alloc(MS_ * 256 * 2);
  bf16* MO    = (bf16*)alloc(MS_ * 512 * 2);
  bf16* CB    = (bf16*)alloc(MS_ * 1024 * 2);

  // 1: all converts/concat/transpose/mask-prep
  fused_prep<<<9479, 256, 0, stream>>>(X, Wq, Wk, Wv, Wo, Wma, Wmp, mask,
                                       bq, bk, bv, mv,
                                       Xb, Wqkvb, Wob, Wmab, Wmpb, M2, bqkv, mvTb);
  // 2: fused QKV projection (V written transposed)
  gemm_qkv<<<dim3(48, 32), 256, 0, stream>>>(Xb, Wqkvb, bqkv, Qb, Kb, Vtb);
  // 3: attention
  attn_fwd<<<dim3(16, 16, 2), 256, 0, stream>>>(Qb, Kb, Vtb, M2, AO);
  // 4-6: memory path
  gemm_bt<float, false><<<dim3(4, 32), 256, 0, stream>>>(Xb, Wmab, bma, nullptr, MSc, 4096, 256, 1024, 1.0f);
  softmax_rows256<<<1024, 256, 0, stream>>>(MSc, MP);
  gemm_bt<bf16, false><<<dim3(8, 32), 256, 0, stream>>>(MP, mvTb, nullptr, nullptr, MO, 4096, 512, 256, 1.0f);
  // 7: combined = attn_out + 0.3*(mem_out @ Wmp^T + bmp)
  gemm_bt<bf16, true><<<dim3(16, 32), 256, 0, stream>>>(MO, Wmpb, bmp, AO, CB, 4096, 1024, 512, 0.3f);
  // 8: final projection -> fp32 out
  gemm_bt<float, false><<<dim3(16, 32), 256, 0, stream>>>(CB, Wob, bo, nullptr, (float*)d_out, 4096, 1024, 1024, 1.0f);
}

// Round 4
// 163.761 us; speedup vs baseline: 1.9198x; 1.0232x over previous
//
#include <hip/hip_runtime.h>

typedef __bf16 bf16;
typedef __bf16 bf16x8 __attribute__((ext_vector_type(8)));
typedef __bf16 bf16x4 __attribute__((ext_vector_type(4)));
typedef float  f32x4  __attribute__((ext_vector_type(4)));
typedef float  f32x16 __attribute__((ext_vector_type(16)));
typedef unsigned u32x2 __attribute__((ext_vector_type(2)));
typedef unsigned u32x4 __attribute__((ext_vector_type(4)));
typedef unsigned long long uptr;

#define MFMA16(a, b, c) __builtin_amdgcn_mfma_f32_16x16x32_bf16((a), (b), (c), 0, 0, 0)
#define MFMA32(a, b, c) __builtin_amdgcn_mfma_f32_32x32x16_bf16((a), (b), (c), 0, 0, 0)

__device__ __forceinline__ void gl_lds16(const void* g, void* l) {
  __builtin_amdgcn_global_load_lds(
      (__attribute__((address_space(1))) void*)(uptr)(g),
      (__attribute__((address_space(3))) void*)(uptr)(l),
      16, 0, 0);
}
__device__ __forceinline__ void gl_lds4(const void* g, void* l) {
  __builtin_amdgcn_global_load_lds(
      (__attribute__((address_space(1))) void*)(uptr)(g),
      (__attribute__((address_space(3))) void*)(uptr)(l),
      4, 0, 0);
}
__device__ __forceinline__ unsigned cvtpk_bf16(float lo, float hi) {
  unsigned r;
  asm("v_cvt_pk_bf16_f32 %0, %1, %2" : "=v"(r) : "v"(lo), "v"(hi));
  return r;
}

// ---------------------------------------------------------------------------
// One fused prep kernel: f32->bf16 converts, QKV weight/bias concat, mask
// premultiply (exp2-domain), memory_values transpose.
__global__ __launch_bounds__(256) void fused_prep(
    const float* __restrict__ X, const float* __restrict__ Wq,
    const float* __restrict__ Wk, const float* __restrict__ Wv,
    const float* __restrict__ Wo, const float* __restrict__ Wma,
    const float* __restrict__ Wmp, const float* __restrict__ mask,
    const float* __restrict__ bq, const float* __restrict__ bk,
    const float* __restrict__ bv, const float* __restrict__ mv,
    bf16* __restrict__ Xb, bf16* __restrict__ Wqkvb, bf16* __restrict__ Wob,
    bf16* __restrict__ Wmab, bf16* __restrict__ Wmpb,
    float* __restrict__ M2, float* __restrict__ bqkv, bf16* __restrict__ mvTb) {
  const int bid = blockIdx.x, t = threadIdx.x;
  auto cvt = [&](const float* src, bf16* dst, int blk) {
    const long i = ((long)blk * 256 + t) * 4;
    const float4 v = *(const float4*)(src + i);
    bf16x4 o = {(bf16)v.x, (bf16)v.y, (bf16)v.z, (bf16)v.w};
    *(bf16x4*)(dst + i) = o;
  };
  if (bid < 4096) cvt(X, Xb, bid);
  else if (bid < 5120) cvt(Wq, Wqkvb, bid - 4096);
  else if (bid < 6144) cvt(Wk, Wqkvb + 1024 * 1024, bid - 5120);
  else if (bid < 7168) cvt(Wv, Wqkvb + 2 * 1024 * 1024, bid - 6144);
  else if (bid < 8192) cvt(Wo, Wob, bid - 7168);
  else if (bid < 8448) cvt(Wma, Wmab, bid - 8192);
  else if (bid < 8960) cvt(Wmp, Wmpb, bid - 8448);
  else if (bid < 8964) {  // mask -> exp2-domain additive
    const long i = ((long)(bid - 8960) * 256 + t) * 4;
    const float4 v = *(const float4*)(mask + i);
    float4 o = {v.x * -1.44269504e9f, v.y * -1.44269504e9f,
                v.z * -1.44269504e9f, v.w * -1.44269504e9f};
    *(float4*)(M2 + i) = o;
  } else if (bid < 8967) {  // bias concat
    const int s = bid - 8964;
    const float* src = s == 0 ? bq : (s == 1 ? bk : bv);
    *(float4*)(bqkv + s * 1024 + t * 4) = *(const float4*)(src + t * 4);
  } else {  // memory_values transpose [256][512] -> [512][256] bf16
    const int d = bid - 8967;
    mvTb[(long)d * 256 + t] = (bf16)mv[(long)t * 512 + d];
  }
}

// row softmax over 256 cols, fp32 in, bf16 out. one wave per row.
__global__ __launch_bounds__(256) void softmax_rows256(const float* __restrict__ in,
                                                       bf16* __restrict__ out) {
  const int w = threadIdx.x >> 6, l = threadIdx.x & 63;
  const long row = (long)blockIdx.x * 4 + w;
  const float4 v = *(const float4*)(in + row * 256 + l * 4);
  float mx = fmaxf(fmaxf(v.x, v.y), fmaxf(v.z, v.w));
  mx = fmaxf(mx, __shfl_xor(mx, 1, 64));
  mx = fmaxf(mx, __shfl_xor(mx, 2, 64));
  mx = fmaxf(mx, __shfl_xor(mx, 4, 64));
  mx = fmaxf(mx, __shfl_xor(mx, 8, 64));
  mx = fmaxf(mx, __shfl_xor(mx, 16, 64));
  mx = fmaxf(mx, __shfl_xor(mx, 32, 64));
  const float e0 = __expf(v.x - mx), e1 = __expf(v.y - mx);
  const float e2 = __expf(v.z - mx), e3 = __expf(v.w - mx);
  float sm = e0 + e1 + e2 + e3;
  sm += __shfl_xor(sm, 1, 64);
  sm += __shfl_xor(sm, 2, 64);
  sm += __shfl_xor(sm, 4, 64);
  sm += __shfl_xor(sm, 8, 64);
  sm += __shfl_xor(sm, 16, 64);
  sm += __shfl_xor(sm, 32, 64);
  const float inv = 1.0f / sm;
  bf16x4 o = {(bf16)(e0 * inv), (bf16)(e1 * inv), (bf16)(e2 * inv), (bf16)(e3 * inv)};
  *(bf16x4*)(out + row * 256 + l * 4) = o;
}

// ---------------------------------------------------------------------------
// Generic GEMM: C[M][N] = (A[M][K] @ B[N][K]^T + bias)*alpha (+ add)
// 128x64 tile, BK=64, 4 waves, double-buffered LDS with prefetch.
template <typename OutT, bool HAS_ADD>
__global__ __launch_bounds__(256, 3) void gemm_bt(
    const bf16* __restrict__ A, const bf16* __restrict__ B,
    const float* __restrict__ bias, const bf16* __restrict__ addsrc,
    OutT* __restrict__ C, int M, int N, int K, float alpha) {
  __shared__ bf16 lA[2][128 * 64];
  __shared__ bf16 lB[2][64 * 64];
  const int tid = threadIdx.x;
  const int w = tid >> 6, l = tid & 63;
  const int hi = l >> 4, lo = l & 15;
  const int m0 = blockIdx.y * 128, n0 = blockIdx.x * 64;
  const int wm = w * 32;

  const int sr8 = l >> 3;
  const int sc = (l & 7) * 8;
  const long aRow = (long)(m0 + wm + sr8);
  const long bRow = (long)(n0 + w * 16 + sr8);

  auto stage = [&](int p, int k0) {
#pragma unroll
    for (int j = 0; j < 4; ++j)
      gl_lds16(A + (aRow + 8 * j) * K + k0 + sc, (char*)lA[p] + (wm + 8 * j) * 128);
#pragma unroll
    for (int j = 0; j < 2; ++j)
      gl_lds16(B + (bRow + 8 * j) * K + k0 + sc, (char*)lB[p] + (w * 16 + 8 * j) * 128);
  };

  f32x4 acc[2][4] = {};
  stage(0, 0);
  __syncthreads();
  const int nt = K >> 6;

  for (int t = 0; t < nt; ++t) {
    const int p = t & 1;
    if (t + 1 < nt) stage(p ^ 1, (t + 1) << 6);
#pragma unroll
    for (int kk = 0; kk < 2; ++kk) {
      bf16x8 af[2], bfr[4];
#pragma unroll
      for (int mi = 0; mi < 2; ++mi)
        af[mi] = *(const bf16x8*)((const char*)lA[p] + (wm + mi * 16 + lo) * 128 + kk * 64 + hi * 16);
#pragma unroll
      for (int ni = 0; ni < 4; ++ni)
        bfr[ni] = *(const bf16x8*)((const char*)lB[p] + (ni * 16 + lo) * 128 + kk * 64 + hi * 16);
      __builtin_amdgcn_s_setprio(1);
#pragma unroll
      for (int mi = 0; mi < 2; ++mi)
#pragma unroll
        for (int ni = 0; ni < 4; ++ni)
          acc[mi][ni] = MFMA16(af[mi], bfr[ni], acc[mi][ni]);
      __builtin_amdgcn_s_setprio(0);
    }
    __syncthreads();
  }

#pragma unroll
  for (int ni = 0; ni < 4; ++ni) {
    const int col = n0 + ni * 16 + lo;
    const float bv = bias ? bias[col] : 0.0f;
#pragma unroll
    for (int mi = 0; mi < 2; ++mi) {
      const int mrow = m0 + wm + mi * 16 + hi * 4;
#pragma unroll
      for (int r = 0; r < 4; ++r) {
        const long row = mrow + r;
        float v = (acc[mi][ni][r] + bv) * alpha;
        if (HAS_ADD) v += (float)addsrc[row * N + col];
        C[row * (long)N + col] = (OutT)v;
      }
    }
  }
}

// Fused QKV projection, m97 128x128 structure (single-buffer, 2 barriers/K-step).
// A[4096][1024] @ Wqkv[3072][1024]^T + bqkv.
// cols 0..1023 -> Q, 1024..2047 -> K, 2048..3071 -> V transposed [B][h*64+d][S].
__global__ __launch_bounds__(256, 3) void gemm_qkv(
    const bf16* __restrict__ A, const bf16* __restrict__ B,
    const float* __restrict__ bias, bf16* __restrict__ Qo,
    bf16* __restrict__ Ko, bf16* __restrict__ Vto) {
  const int K = 1024;
  __shared__ bf16 lA[128 * 64];
  __shared__ bf16 lB[128 * 64];
  const int tid = threadIdx.x;
  const int w = tid >> 6, l = tid & 63;
  const int hi = l >> 4, lo = l & 15;
  const int m0 = blockIdx.y * 128, n0 = blockIdx.x * 128;
  const int wm = (w >> 1) * 64, wn = (w & 1) * 64;

  const int sr = w * 32 + (l >> 3);
  const int sc = (l & 7) * 8;
  const long aBase = (long)(m0 + sr) * K + sc;
  const long bBase = (long)(n0 + sr) * K + sc;

  f32x4 acc[4][4] = {};

  for (int k0 = 0; k0 < K; k0 += 64) {
#pragma unroll
    for (int j = 0; j < 4; ++j) {
      gl_lds16(A + aBase + (long)8 * j * K + k0, (char*)lA + (w * 32 + 8 * j) * 128);
      gl_lds16(B + bBase + (long)8 * j * K + k0, (char*)lB + (w * 32 + 8 * j) * 128);
    }
    __syncthreads();
#pragma unroll
    for (int kk = 0; kk < 2; ++kk) {
      bf16x8 af[4], bfr[4];
#pragma unroll
      for (int i = 0; i < 4; ++i) {
        af[i]  = *(const bf16x8*)((const char*)lA + (wm + i * 16 + lo) * 128 + kk * 64 + hi * 16);
        bfr[i] = *(const bf16x8*)((const char*)lB + (wn + i * 16 + lo) * 128 + kk * 64 + hi * 16);
      }
#pragma unroll
      for (int mi = 0; mi < 4; ++mi)
#pragma unroll
        for (int ni = 0; ni < 4; ++ni)
          acc[mi][ni] = MFMA16(af[mi], bfr[ni], acc[mi][ni]);
    }
    __syncthreads();
  }

  const int region = n0 >> 10;  // 0=Q 1=K 2=V (128-col block never straddles)
#pragma unroll
  for (int ni = 0; ni < 4; ++ni) {
    const int col = n0 + wn + ni * 16 + lo;
    const float bv = bias[col];
#pragma unroll
    for (int mi = 0; mi < 4; ++mi) {
      const int mrow = m0 + wm + mi * 16 + hi * 4;
#pragma unroll
      for (int r = 0; r < 4; ++r) {
        const long row = mrow + r;
        const float v = acc[mi][ni][r] + bv;
        if (region == 0) {
          Qo[row * 1024 + col] = (bf16)v;
        } else if (region == 1) {
          Ko[row * 1024 + (col - 1024)] = (bf16)v;
        } else {
          const long bb = row >> 11, ss = row & 2047;
          Vto[(bb * 1024 + (col - 2048)) * 2048 + ss] = (bf16)v;
        }
      }
    }
  }
}

// ---------------------------------------------------------------------------
// Flash attention, swapped-QK^T 32x32 structure, KEY-SPLIT x2.
// Q,K: [B*S][1024] bf16; Vt: [B][1024=h*64+d][S] bf16; M2: mask*(-1e9*log2e).
// grid (16 q-tiles, 16 heads, 4 = b*2+half). Each block: 128 q x 1024 keys.
// Outputs UNNORMALIZED bf16 O-partials + (m,l) f32 per (q,head,half).
__global__ __launch_bounds__(256, 4) void attn_fwd(
    const bf16* __restrict__ Q, const bf16* __restrict__ Km,
    const bf16* __restrict__ Vt, const float* __restrict__ M2,
    bf16* __restrict__ Opart, float* __restrict__ ml) {
  __shared__ bf16 lK[2][64 * 64];
  __shared__ bf16 lV[2][64 * 64];
  __shared__ alignas(16) float lM[2][64];
  const int tid = threadIdx.x, w = tid >> 6, l = tid & 63;
  const int q31 = l & 31, h32 = l >> 5;
  const int b = blockIdx.z >> 1, half = blockIdx.z & 1;
  const int hh = blockIdx.y, q0 = blockIdx.x * 128;
  const long S = 2048, H = 1024;
  const int kbase = half * 1024;
  const float SCALE2 = 0.125f * 1.44269504f;

  // Q as B-operand: col=lane&31=q, k=(lane>>5)*8+j; 4 slices of 16 over d=64
  bf16x8 qf[4];
  const long qrow = (long)b * S + q0 + w * 32 + q31;
#pragma unroll
  for (int sl = 0; sl < 4; ++sl)
    qf[sl] = *(const bf16x8*)(Q + qrow * H + hh * 64 + sl * 16 + h32 * 8);

  f32x16 o0 = {}, o1 = {};
  float mrun = -1e30f, lrun = 0.0f;

  const int swr = w * 16 + (l >> 3);
  const int swc = ((l & 7) ^ (l >> 3)) * 8;

  auto stage = [&](int p, int k0) {
#pragma unroll
    for (int j = 0; j < 2; ++j) {
      gl_lds16(Km + ((long)b * S + k0 + swr + 8 * j) * H + hh * 64 + swc,
               (char*)lK[p] + (w * 16 + 8 * j) * 128);
      gl_lds16(Vt + ((long)b * H + hh * 64 + swr + 8 * j) * S + k0 + swc,
               (char*)lV[p] + (w * 16 + 8 * j) * 128);
    }
    if (w == 0) gl_lds4(M2 + (long)b * S + k0 + l, (char*)lM[p]);
  };

  stage(0, kbase);
  __syncthreads();

  for (int t = 0; t < 16; ++t) {
    const int p = t & 1;
    if (t < 15) stage(p ^ 1, kbase + (t + 1) * 64);

    // S = K Q^T (swapped): D[key][q], q = lane&31
    f32x16 s0 = {}, s1 = {};
    __builtin_amdgcn_s_setprio(1);
#pragma unroll
    for (int sl = 0; sl < 4; ++sl) {
      const int ch = sl * 2 + h32;
      const int cx = (ch ^ (q31 & 7)) * 16;
      const bf16x8 k0f = *(const bf16x8*)((const char*)lK[p] + q31 * 128 + cx);
      const bf16x8 k1f = *(const bf16x8*)((const char*)lK[p] + (32 + q31) * 128 + cx);
      s0 = MFMA32(k0f, qf[sl], s0);
      s1 = MFMA32(k1f, qf[sl], s1);
    }
    __builtin_amdgcn_s_setprio(0);

    // scale + additive mask (exp2 domain); reg->key row = (reg&3)+8*(reg>>2)+4*h32
#pragma unroll
    for (int g = 0; g < 4; ++g) {
      const f32x4 m0 = *(const f32x4*)&lM[p][8 * g + 4 * h32];
      const f32x4 m1 = *(const f32x4*)&lM[p][32 + 8 * g + 4 * h32];
#pragma unroll
      for (int r = 0; r < 4; ++r) {
        s0[4 * g + r] = s0[4 * g + r] * SCALE2 + m0[r];
        s1[4 * g + r] = s1[4 * g + r] * SCALE2 + m1[r];
      }
    }

    // row max: in-lane tree + one cross-half shuffle
    f32x16 tm;
#pragma unroll
    for (int i = 0; i < 16; ++i) tm[i] = fmaxf(s0[i], s1[i]);
#pragma unroll
    for (int i = 0; i < 8; ++i) tm[i] = fmaxf(tm[i], tm[i + 8]);
#pragma unroll
    for (int i = 0; i < 4; ++i) tm[i] = fmaxf(tm[i], tm[i + 4]);
    float mx = fmaxf(fmaxf(tm[0], tm[1]), fmaxf(tm[2], tm[3]));
    mx = fmaxf(mx, __shfl_xor(mx, 32, 64));

    // defer-max (T13)
    if (__any(mx > mrun + 8.0f)) {
      const float mn = fmaxf(mrun, mx);
      const float f = __builtin_amdgcn_exp2f(mrun - mn);
      mrun = mn;
      lrun *= f;
      float fb[16];
#pragma unroll
      for (int reg = 0; reg < 16; ++reg)
        fb[reg] = __shfl(f, (reg & 3) + 8 * (reg >> 2) + 4 * h32, 64);
#pragma unroll
      for (int reg = 0; reg < 16; ++reg) { o0[reg] *= fb[reg]; o1[reg] *= fb[reg]; }
    }

    // P = exp2(s - m)
#pragma unroll
    for (int i = 0; i < 16; ++i) s0[i] = __builtin_amdgcn_exp2f(s0[i] - mrun);
#pragma unroll
    for (int i = 0; i < 16; ++i) s1[i] = __builtin_amdgcn_exp2f(s1[i] - mrun);

    // row sum: in-lane tree + one cross-half shuffle
    f32x16 ts;
#pragma unroll
    for (int i = 0; i < 16; ++i) ts[i] = s0[i] + s1[i];
#pragma unroll
    for (int i = 0; i < 8; ++i) ts[i] += ts[i + 8];
#pragma unroll
    for (int i = 0; i < 4; ++i) ts[i] += ts[i + 4];
    float rs = (ts[0] + ts[1]) + (ts[2] + ts[3]);
    rs += __shfl_xor(rs, 32, 64);
    lrun += rs;

    // P (C-layout f32) -> PV A-frags: cvt_pk + permlane32_swap (T12)
    bf16x8 pa[4];
#pragma unroll
    for (int ks = 0; ks < 4; ++ks) {
      const int rb = (ks & 1) * 8;
      unsigned a0, a1, b0, b1;
      if (ks < 2) {
        a0 = cvtpk_bf16(s0[rb + 0], s0[rb + 1]);
        a1 = cvtpk_bf16(s0[rb + 2], s0[rb + 3]);
        b0 = cvtpk_bf16(s0[rb + 4], s0[rb + 5]);
        b1 = cvtpk_bf16(s0[rb + 6], s0[rb + 7]);
      } else {
        a0 = cvtpk_bf16(s1[rb + 0], s1[rb + 1]);
        a1 = cvtpk_bf16(s1[rb + 2], s1[rb + 3]);
        b0 = cvtpk_bf16(s1[rb + 4], s1[rb + 5]);
        b1 = cvtpk_bf16(s1[rb + 6], s1[rb + 7]);
      }
      const u32x2 r02 = __builtin_amdgcn_permlane32_swap(a0, b0, false, false);
      const u32x2 r13 = __builtin_amdgcn_permlane32_swap(a1, b1, false, false);
      const u32x4 pw = {r02[0], r13[0], r02[1], r13[1]};
      pa[ks] = __builtin_bit_cast(bf16x8, pw);
    }

    // O += P V  (B-frag of V from lV[d][key], same XOR swizzle)
    __builtin_amdgcn_s_setprio(1);
#pragma unroll
    for (int ks = 0; ks < 4; ++ks) {
      const int ch = ks * 2 + h32;
      const int cx = (ch ^ (q31 & 7)) * 16;
      const bf16x8 v0 = *(const bf16x8*)((const char*)lV[p] + q31 * 128 + cx);
      const bf16x8 v1 = *(const bf16x8*)((const char*)lV[p] + (32 + q31) * 128 + cx);
      o0 = MFMA32(pa[ks], v0, o0);
      o1 = MFMA32(pa[ks], v1, o1);
    }
    __builtin_amdgcn_s_setprio(0);
    __syncthreads();
  }

  // epilogue: per-(q,h,half) m/l (lane&31 = q, lower half) + unnormalized O
  if (h32 == 0) {
    float2 v = {mrun, lrun};
    ((float2*)ml)[((long)half * 4096 + (long)b * 2048 + q0 + w * 32 + q31) * 16 + hh] = v;
  }
#pragma unroll
  for (int reg = 0; reg < 16; ++reg) {
    const int row = (reg & 3) + 8 * (reg >> 2) + 4 * h32;
    const long qg = (long)b * 2048 + q0 + w * 32 + row;
    Opart[((long)half * 4096 + qg) * 1024 + hh * 64 + q31]      = (bf16)o0[reg];
    Opart[((long)half * 4096 + qg) * 1024 + hh * 64 + 32 + q31] = (bf16)o1[reg];
  }
}

// Combine the two key-half partials: AO = (w0*O0 + w1*O1) / (w0*l0 + w1*l1)
__global__ __launch_bounds__(256) void attn_combine(
    const bf16* __restrict__ Opart, const float* __restrict__ ml,
    bf16* __restrict__ AO) {
  const long i = ((long)blockIdx.x * 256 + threadIdx.x) * 4;
  const long qg = i >> 10;
  const int h = (int)((i & 1023) >> 6);
  const float2 a = ((const float2*)ml)[qg * 16 + h];
  const float2 c = ((const float2*)ml)[(4096 + qg) * 16 + h];
  const float m = fmaxf(a.x, c.x);
  const float w0 = __builtin_amdgcn_exp2f(a.x - m);
  const float w1 = __builtin_amdgcn_exp2f(c.x - m);
  const float inv = 1.0f / (w0 * a.y + w1 * c.y);
  const bf16x4 O0 = *(const bf16x4*)(Opart + i);
  const bf16x4 O1 = *(const bf16x4*)(Opart + 4096L * 1024 + i);
  bf16x4 o;
#pragma unroll
  for (int j = 0; j < 4; ++j)
    o[j] = (bf16)(((float)O0[j] * w0 + (float)O1[j] * w1) * inv);
  *(bf16x4*)(AO + i) = o;
}

// ---------------------------------------------------------------------------
extern "C" void kernel_launch(void* const* d_in, const int* in_sizes, int n_in,
                              void* d_out, int out_size, void* d_ws, size_t ws_size,
                              hipStream_t stream) {
  const float* X    = (const float*)d_in[0];
  const float* mask = (const float*)d_in[1];
  const float* Wq   = (const float*)d_in[2];  const float* bq  = (const float*)d_in[3];
  const float* Wk   = (const float*)d_in[4];  const float* bk  = (const float*)d_in[5];
  const float* Wv   = (const float*)d_in[6];  const float* bv  = (const float*)d_in[7];
  const float* Wo   = (const float*)d_in[8];  const float* bo  = (const float*)d_in[9];
  const float* mv   = (const float*)d_in[10];
  const float* Wmp  = (const float*)d_in[11]; const float* bmp = (const float*)d_in[12];
  const float* Wma  = (const float*)d_in[13]; const float* bma = (const float*)d_in[14];

  char* ws = (char*)d_ws;
  size_t off = 0;
  auto alloc = [&](size_t bytes) -> void* {
    void* p = ws + off;
    off += (bytes + 255) & ~(size_t)255;
    return p;
  };
  const long MS_ = 4096;  // B*S rows
  bf16* Xb    = (bf16*)alloc(MS_ * 1024 * 2);
  bf16* Wqkvb = (bf16*)alloc(3072L * 1024 * 2);
  bf16* Wob   = (bf16*)alloc(1024 * 1024 * 2);
  bf16* Wmab  = (bf16*)alloc(256 * 1024 * 2);
  bf16* Wmpb  = (bf16*)alloc(1024 * 512 * 2);
  bf16* mvTb  = (bf16*)alloc(512 * 256 * 2);
  float* M2   = (float*)alloc(MS_ * 4);
  float* bqkv = (float*)alloc(3072 * 4);
  bf16* Qb    = (bf16*)alloc(MS_ * 1024 * 2);
  bf16* Kb    = (bf16*)alloc(MS_ * 1024 * 2);
  bf16* Vtb   = (bf16*)alloc(MS_ * 1024 * 2);  // [B][h*64+d][S]
  bf16* AO    = (bf16*)alloc(MS_ * 1024 * 2);
  // shared region: attn partials (live attn->combine), then memory-path scratch
  char* region = (char*)alloc(2 * MS_ * 1024 * 2 + MS_ * 16 * 8 + 1024);
  bf16* Opart = (bf16*)region;                           // [2][4096][1024] bf16 = 16MB
  float* ml   = (float*)(region + 2 * MS_ * 1024 * 2);   // [2][4096][16] float2 = 1MB
  float* MSc  = (float*)region;                          // 4MB  (after combine)
  bf16* MP    = (bf16*)(region + MS_ * 256 * 4);         // 2MB
  bf16* MO    = Kb;                                      // dead after attn
  bf16* CB    = Qb;                                      // dead after attn

  // 1: all converts/concat/transpose/mask-prep
  fused_prep<<<9479, 256, 0, stream>>>(X, Wq, Wk, Wv, Wo, Wma, Wmp, mask,
                                       bq, bk, bv, mv,
                                       Xb, Wqkvb, Wob, Wmab, Wmpb, M2, bqkv, mvTb);
  // 2: fused QKV projection, 128x128 m97 tile (V written transposed)
  gemm_qkv<<<dim3(24, 32), 256, 0, stream>>>(Xb, Wqkvb, bqkv, Qb, Kb, Vtb);
  // 3: attention, key-split x2 + combine
  attn_fwd<<<dim3(16, 16, 4), 256, 0, stream>>>(Qb, Kb, Vtb, M2, Opart, ml);
  attn_combine<<<4096, 256, 0, stream>>>(Opart, ml, AO);
  // 4-6: memory path
  gemm_bt<float, false><<<dim3(4, 32), 256, 0, stream>>>(Xb, Wmab, bma, nullptr, MSc, 4096, 256, 1024, 1.0f);
  softmax_rows256<<<1024, 256, 0, stream>>>(MSc, MP);
  gemm_bt<bf16, false><<<dim3(8, 32), 256, 0, stream>>>(MP, mvTb, nullptr, nullptr, MO, 4096, 512, 256, 1.0f);
  // 7: combined = attn_out + 0.3*(mem_out @ Wmp^T + bmp)
  gemm_bt<bf16, true><<<dim3(16, 32), 256, 0, stream>>>(MO, Wmpb, bmp, AO, CB, 4096, 1024, 512, 0.3f);
  // 8: final projection -> fp32 out
  gemm_bt<float, false><<<dim3(16, 32), 256, 0, stream>>>(CB, Wob, bo, nullptr, (float*)d_out, 4096, 1024, 1024, 1.0f);
}